// Round 9
// baseline (237.244 us; speedup 1.0000x reference)
//
#include <hip/hip_runtime.h>
#include <hip/hip_fp16.h>

#define SEQ 8192
#define CHUNK 32               // k-tiles (16 keys each) per wave chunk

// v2 geometry: 256 q-supertiles of 32 rows; nk(st) = 2st+2 k-tiles
#define NST 256
#define TOTAL_CHUNKS2 2176     // sum over st of ceil((2st+2)/32)

// v1 (control probe) geometry: 512 q-tiles of 16 rows
#define NQT1 512
#define TOTAL_CHUNKS1 4352

typedef _Float16 half4  __attribute__((ext_vector_type(4)));
typedef _Float16 half8  __attribute__((ext_vector_type(8)));
typedef float   floatx4 __attribute__((ext_vector_type(4)));

__device__ __forceinline__ int cum1(int n) {   // v1: chunks for q-tiles 0..n-1
    const int a = n >> 5, r = n & 31;
    return n + 16 * a * (a - 1) + a * r;
}
__device__ __forceinline__ int cum2(int n) {   // v2: chunks for supertiles 0..n-1
    const int a = n >> 4, r = n & 15;          // ceil((2j+2)/32) = ceil((j+1)/16)
    return (a + 1) * (8 * a + r);
}

// ---------------- Kernel 1: QKV projection (round-4 verified) -------------
__global__ __launch_bounds__(256) void proj_kernel(
    const float* __restrict__ x,
    const float* __restrict__ Wq, const float* __restrict__ bq,
    const float* __restrict__ Wk, const float* __restrict__ bk,
    const float* __restrict__ Wv, const float* __restrict__ bv,
    _Float16* __restrict__ Q, _Float16* __restrict__ KV)
{
    __shared__ float4 xs[16][17];
    __shared__ float4 wqs[16][17];
    __shared__ float4 wks[16][17];
    __shared__ float4 wvs[16][17];

    const int tid  = threadIdx.x;
    const int r    = tid >> 4;
    const int d    = tid & 15;
    const int row0 = blockIdx.x * 16;

    const int rr  = tid >> 4;
    const int cc4 = tid & 15;
    xs[rr][cc4]  = *(const float4*)(x  + (size_t)row0 * 64 + tid * 4);
    wqs[rr][cc4] = *(const float4*)(Wq + tid * 4);
    wks[rr][cc4] = *(const float4*)(Wk + tid * 4);
    wvs[rr][cc4] = *(const float4*)(Wv + tid * 4);
    __syncthreads();

    float aq = 0.f, ak = 0.f, av = 0.f;
#pragma unroll
    for (int kk = 0; kk < 16; ++kk) {
        const float4 xv = xs[r][kk];
        const float4 q4 = wqs[d][kk];
        const float4 k4 = wks[d][kk];
        const float4 v4 = wvs[d][kk];
        aq += xv.x * q4.x; aq += xv.y * q4.y; aq += xv.z * q4.z; aq += xv.w * q4.w;
        ak += xv.x * k4.x; ak += xv.y * k4.y; ak += xv.z * k4.z; ak += xv.w * k4.w;
        av += xv.x * v4.x; av += xv.y * v4.y; av += xv.z * v4.z; av += xv.w * v4.w;
    }
    aq += bq[d];
    ak += bk[d];
    av += bv[d];
    aq *= 0.36067376022224085f;   // (1/sqrt(16)) * log2(e)

    const int row = row0 + r;
    Q[row * 16 + d] = (_Float16)aq;
    _Float16* kvb = KV + (size_t)blockIdx.x * 512;
    kvb[((d >> 2) * 16 + r) * 8 + (d & 3)]     = (_Float16)ak;
    kvb[((r >> 2) * 16 + d) * 8 + 4 + (r & 3)] = (_Float16)av;
}

// ---------------- Kernel 2 (v2): 2-q-tile flash, KV shared ----------------
// Chunk = <=32 k-tiles x 32 q-rows (supertile). Each KV tile loaded ONCE
// serves TWO q-frags: halves VMEM/movs/loop overhead per S-element, and
// gives each wave 2 independent MFMA chains. Mask-free tiles end at
// td0 = 2*st; td0 is diagonal for the lower 16 rows and full for the upper;
// td1 = td0+1 is diagonal for the upper and empty for the lower.
template <int REP>
__global__ __launch_bounds__(64) void flash_v2(
    const _Float16* __restrict__ Q, const _Float16* __restrict__ KV,
    float* __restrict__ partO, float* __restrict__ partL)
{
    const int bp = (TOTAL_CHUNKS2 - 1) - (int)blockIdx.x;   // biggest first
    int lo = 0, hi = NST - 1;
#pragma unroll
    for (int it = 0; it < 8; ++it) {          // 2^8 = 256 = NST
        const int mid = (lo + hi + 1) >> 1;
        if (cum2(mid) <= bp) lo = mid; else hi = mid - 1;
    }
    const int st = lo;
    const int c  = bp - cum2(st);
    const int t0 = c * CHUNK;
    const int nk = 2 * st + 2;                // total k-tiles incl. diagonals
    int t1 = t0 + CHUNK;
    if (t1 > nk) t1 = nk;
    const int td0 = 2 * st;
    const int nd  = (t1 < td0) ? t1 : td0;    // end of mask-free tiles

    const int L    = threadIdx.x;
    const int m16  = L & 15;
    const int quad = L >> 4;
    const int qrA  = st * 32 + m16;           // lower-half q-row
    const int qrB  = qrA + 16;                // upper-half q-row

    const half4 qfA = *(const half4*)(Q + (size_t)qrA * 16 + quad * 4);
    const half4 qfB = *(const half4*)(Q + (size_t)qrB * 16 + quad * 4);
    const _Float16* kvbase = KV + (size_t)L * 8;   // + t*512 halfs per tile

    const floatx4 z4 = {0.f, 0.f, 0.f, 0.f};

    auto ldkv = [&](int t) -> half8 {
        return *(const half8*)(kvbase + (size_t)t * 512);
    };

    for (int rep = 0; rep < REP; ++rep) {
        float   lA = 0.f, lB = 0.f;
        floatx4 accA = {0.f, 0.f, 0.f, 0.f};
        floatx4 accB = {0.f, 0.f, 0.f, 0.f};

        auto body2 = [&](half8 kv) {
            const half4 kf = __builtin_shufflevector(kv, kv, 0, 1, 2, 3);
            const half4 vf = __builtin_shufflevector(kv, kv, 4, 5, 6, 7);
            floatx4 sA = __builtin_amdgcn_mfma_f32_16x16x16f16(kf, qfA, z4, 0, 0, 0);
            floatx4 sB = __builtin_amdgcn_mfma_f32_16x16x16f16(kf, qfB, z4, 0, 0, 0);
            const float a0 = __builtin_amdgcn_exp2f(sA[0]);
            const float a1 = __builtin_amdgcn_exp2f(sA[1]);
            const float a2 = __builtin_amdgcn_exp2f(sA[2]);
            const float a3 = __builtin_amdgcn_exp2f(sA[3]);
            const float b0 = __builtin_amdgcn_exp2f(sB[0]);
            const float b1 = __builtin_amdgcn_exp2f(sB[1]);
            const float b2 = __builtin_amdgcn_exp2f(sB[2]);
            const float b3 = __builtin_amdgcn_exp2f(sB[3]);
            lA += (a0 + a1) + (a2 + a3);
            lB += (b0 + b1) + (b2 + b3);
            const half4 pA = {(_Float16)a0, (_Float16)a1, (_Float16)a2, (_Float16)a3};
            const half4 pB = {(_Float16)b0, (_Float16)b1, (_Float16)b2, (_Float16)b3};
            accA = __builtin_amdgcn_mfma_f32_16x16x16f16(vf, pA, accA, 0, 0, 0);
            accB = __builtin_amdgcn_mfma_f32_16x16x16f16(vf, pB, accB, 0, 0, 0);
        };

        // mask-free tiles (nd - t0 is always even)
        int kt = t0;
        if (kt + 1 < nd) {
            half8 v0 = ldkv(kt);
            half8 v1 = ldkv(kt + 1);
            for (; kt + 3 < nd; kt += 2) {
                const half8 n0 = ldkv(kt + 2);
                const half8 n1 = ldkv(kt + 3);
                __builtin_amdgcn_s_setprio(1);
                body2(v0);
                body2(v1);
                __builtin_amdgcn_s_setprio(0);
                v0 = n0; v1 = n1;
            }
            body2(v0);
            body2(v1);
            kt += 2;
        }

        if (t1 == nk) {                       // last chunk: diagonal tiles
            {   // td0: diagonal for A, full for B
                const half8 kv = ldkv(td0);
                const half4 kf = __builtin_shufflevector(kv, kv, 0, 1, 2, 3);
                const half4 vf = __builtin_shufflevector(kv, kv, 4, 5, 6, 7);
                floatx4 sA = __builtin_amdgcn_mfma_f32_16x16x16f16(kf, qfA, z4, 0, 0, 0);
#pragma unroll
                for (int r = 0; r < 4; ++r)
                    if (quad * 4 + r > m16) sA[r] = -1.0e30f;
                floatx4 sB = __builtin_amdgcn_mfma_f32_16x16x16f16(kf, qfB, z4, 0, 0, 0);
                const float a0 = __builtin_amdgcn_exp2f(sA[0]);
                const float a1 = __builtin_amdgcn_exp2f(sA[1]);
                const float a2 = __builtin_amdgcn_exp2f(sA[2]);
                const float a3 = __builtin_amdgcn_exp2f(sA[3]);
                const float b0 = __builtin_amdgcn_exp2f(sB[0]);
                const float b1 = __builtin_amdgcn_exp2f(sB[1]);
                const float b2 = __builtin_amdgcn_exp2f(sB[2]);
                const float b3 = __builtin_amdgcn_exp2f(sB[3]);
                lA += (a0 + a1) + (a2 + a3);
                lB += (b0 + b1) + (b2 + b3);
                const half4 pA = {(_Float16)a0, (_Float16)a1, (_Float16)a2, (_Float16)a3};
                const half4 pB = {(_Float16)b0, (_Float16)b1, (_Float16)b2, (_Float16)b3};
                accA = __builtin_amdgcn_mfma_f32_16x16x16f16(vf, pA, accA, 0, 0, 0);
                accB = __builtin_amdgcn_mfma_f32_16x16x16f16(vf, pB, accB, 0, 0, 0);
            }
            {   // td1: diagonal for B, empty for A
                const half8 kv = ldkv(td0 + 1);
                const half4 kf = __builtin_shufflevector(kv, kv, 0, 1, 2, 3);
                const half4 vf = __builtin_shufflevector(kv, kv, 4, 5, 6, 7);
                floatx4 sB = __builtin_amdgcn_mfma_f32_16x16x16f16(kf, qfB, z4, 0, 0, 0);
#pragma unroll
                for (int r = 0; r < 4; ++r)
                    if (quad * 4 + r > m16) sB[r] = -1.0e30f;
                const float b0 = __builtin_amdgcn_exp2f(sB[0]);
                const float b1 = __builtin_amdgcn_exp2f(sB[1]);
                const float b2 = __builtin_amdgcn_exp2f(sB[2]);
                const float b3 = __builtin_amdgcn_exp2f(sB[3]);
                lB += (b0 + b1) + (b2 + b3);
                const half4 pB = {(_Float16)b0, (_Float16)b1, (_Float16)b2, (_Float16)b3};
                accB = __builtin_amdgcn_mfma_f32_16x16x16f16(vf, pB, accB, 0, 0, 0);
            }
        }

        lA += __shfl_xor(lA, 16);
        lA += __shfl_xor(lA, 32);
        lB += __shfl_xor(lB, 16);
        lB += __shfl_xor(lB, 32);

        float* po = partO + (size_t)bp * 512;
        *(floatx4*)(po + m16 * 16 + quad * 4)       = accA;
        *(floatx4*)(po + 256 + m16 * 16 + quad * 4) = accB;
        if (quad == 0) {
            partL[(size_t)bp * 32 + m16]      = lA;
            partL[(size_t)bp * 32 + 16 + m16] = lB;
        }
    }
}

// ---------------- Kernel 2 (v1): round-6 control, probe only --------------
template <int REP>
__global__ __launch_bounds__(64) void flash_v1(
    const _Float16* __restrict__ Q, const _Float16* __restrict__ KV,
    float* __restrict__ partO, float* __restrict__ partL)
{
    const int bp = (TOTAL_CHUNKS1 - 1) - (int)blockIdx.x;
    int lo = 0, hi = NQT1 - 1;
#pragma unroll
    for (int it = 0; it < 9; ++it) {
        const int mid = (lo + hi + 1) >> 1;
        if (cum1(mid) <= bp) lo = mid; else hi = mid - 1;
    }
    const int qt = lo;
    const int c  = bp - cum1(qt);
    const int t0 = c * CHUNK;
    int t1 = t0 + CHUNK;
    if (t1 > qt + 1) t1 = qt + 1;
    const int nd = (t1 > qt) ? qt : t1;

    const int L    = threadIdx.x;
    const int m16  = L & 15;
    const int quad = L >> 4;
    const int qrow = qt * 16 + m16;

    const half4 qf = *(const half4*)(Q + (size_t)qrow * 16 + quad * 4);
    const _Float16* kvbase = KV + (size_t)L * 8;
    const floatx4 z4 = {0.f, 0.f, 0.f, 0.f};

    auto ldkv = [&](int t) -> half8 {
        return *(const half8*)(kvbase + (size_t)t * 512);
    };

    for (int rep = 0; rep < REP; ++rep) {
        float   l0 = 0.f, l1 = 0.f;
        floatx4 acc0 = {0.f, 0.f, 0.f, 0.f};
        floatx4 acc1 = {0.f, 0.f, 0.f, 0.f};

        auto body = [&](half8 kv, floatx4& acc, float& ls) {
            const half4 kf = __builtin_shufflevector(kv, kv, 0, 1, 2, 3);
            const half4 vf = __builtin_shufflevector(kv, kv, 4, 5, 6, 7);
            floatx4 s = __builtin_amdgcn_mfma_f32_16x16x16f16(kf, qf, z4, 0, 0, 0);
            const float p0 = __builtin_amdgcn_exp2f(s[0]);
            const float p1 = __builtin_amdgcn_exp2f(s[1]);
            const float p2 = __builtin_amdgcn_exp2f(s[2]);
            const float p3 = __builtin_amdgcn_exp2f(s[3]);
            ls += (p0 + p1) + (p2 + p3);
            const half4 pf = {(_Float16)p0, (_Float16)p1, (_Float16)p2, (_Float16)p3};
            acc = __builtin_amdgcn_mfma_f32_16x16x16f16(vf, pf, acc, 0, 0, 0);
        };

        int kt = t0;
        if (nd - kt >= 4) {
            half8 b0 = ldkv(kt);
            half8 b1 = ldkv(kt + 1);
            half8 b2 = ldkv(kt + 2);
            half8 b3 = ldkv(kt + 3);
            for (; kt + 7 < nd; kt += 4) {
                const half8 n0 = ldkv(kt + 4);
                const half8 n1 = ldkv(kt + 5);
                const half8 n2 = ldkv(kt + 6);
                const half8 n3 = ldkv(kt + 7);
                __builtin_amdgcn_s_setprio(1);
                body(b0, acc0, l0);
                body(b1, acc1, l1);
                body(b2, acc0, l0);
                body(b3, acc1, l1);
                __builtin_amdgcn_s_setprio(0);
                b0 = n0; b1 = n1; b2 = n2; b3 = n3;
            }
            body(b0, acc0, l0);
            body(b1, acc1, l1);
            body(b2, acc0, l0);
            body(b3, acc1, l1);
            kt += 4;
        }
        for (; kt + 1 < nd; kt += 2) {
            body(ldkv(kt),     acc0, l0);
            body(ldkv(kt + 1), acc1, l1);
        }
        if (kt < nd)
            body(ldkv(kt), acc0, l0);

        if (t1 == qt + 1) {
            const half8 kv = ldkv(qt);
            const half4 kf = __builtin_shufflevector(kv, kv, 0, 1, 2, 3);
            const half4 vf = __builtin_shufflevector(kv, kv, 4, 5, 6, 7);
            floatx4 s = __builtin_amdgcn_mfma_f32_16x16x16f16(kf, qf, z4, 0, 0, 0);
#pragma unroll
            for (int r = 0; r < 4; ++r)
                if (quad * 4 + r > m16) s[r] = -1.0e30f;
            const float p0 = __builtin_amdgcn_exp2f(s[0]);
            const float p1 = __builtin_amdgcn_exp2f(s[1]);
            const float p2 = __builtin_amdgcn_exp2f(s[2]);
            const float p3 = __builtin_amdgcn_exp2f(s[3]);
            l1 += (p0 + p1) + (p2 + p3);
            const half4 pf = {(_Float16)p0, (_Float16)p1, (_Float16)p2, (_Float16)p3};
            acc1 = __builtin_amdgcn_mfma_f32_16x16x16f16(vf, pf, acc1, 0, 0, 0);
        }

        floatx4 acc = {acc0[0] + acc1[0], acc0[1] + acc1[1],
                       acc0[2] + acc1[2], acc0[3] + acc1[3]};
        float lsum = l0 + l1;
        lsum += __shfl_xor(lsum, 16);
        lsum += __shfl_xor(lsum, 32);

        *(floatx4*)(partO + (size_t)bp * 256 + m16 * 16 + quad * 4) = acc;
        if (quad == 0) partL[(size_t)bp * 16 + m16] = lsum;
    }
}

// ---------------- Kernel 3 (v2): merge over supertile chunks --------------
__global__ __launch_bounds__(256) void merge_v2(
    const float* __restrict__ partO, const float* __restrict__ partL,
    float* __restrict__ out)
{
    const int qt = blockIdx.x;            // 512 q-tiles (16 rows)
    const int t  = threadIdx.x;           // q = t>>4, d = t&15
    const int st = qt >> 1;
    const int hf = qt & 1;                // 0 = lower half, 1 = upper half

    const int base = cum2(st);
    const int nc   = (st >> 4) + 1;       // ceil((2st+2)/32)

    const float* po = partO + (size_t)base * 512 + hf * 256 + t;
    const float* pl = partL + (size_t)base * 32 + hf * 16 + (t >> 4);
    float Ls = 0.f, O = 0.f;
    for (int c = 0; c < nc; ++c, po += 512, pl += 32) {
        O  += *po;
        Ls += *pl;
    }
    out[(size_t)qt * 256 + t] = O / Ls;
}

// Production = v2 path (correctness validated by harness this round).
// Probes: flash_v1<10> vs flash_v2<10> on scratch -> within-run A/B in the
// top-5 counter table. Headline dur_us inflated by ~170us of probes.
extern "C" void kernel_launch(void* const* d_in, const int* in_sizes, int n_in,
                              void* d_out, int out_size, void* d_ws, size_t ws_size,
                              hipStream_t stream) {
    const float* x  = (const float*)d_in[0];
    const float* Wq = (const float*)d_in[1];
    const float* bq = (const float*)d_in[2];
    const float* Wk = (const float*)d_in[3];
    const float* bk = (const float*)d_in[4];
    const float* Wv = (const float*)d_in[5];
    const float* bv = (const float*)d_in[6];

    char* ws = (char*)d_ws;
    _Float16* Q     = (_Float16*)(ws);            // 256 KiB
    _Float16* KV    = (_Float16*)(ws + 262144);   // 512 KiB
    float*    partO = (float*)(ws + 786432);      // 2176*512*4 = 4.456 MiB
    float*    partL = (float*)(ws + 786432 + 4456448);  // 2176*32*4 = 278.5 KiB

    // probe scratch
    char* sc = ws + (32u << 20);
    float* pO1 = (float*)(sc);                    // v1: 4.456 MiB
    float* pL1 = (float*)(sc + 5242880);          // v1: 272 KiB
    float* pO2 = (float*)(sc + 6291456);          // v2: 4.456 MiB
    float* pL2 = (float*)(sc + 11534336);         // v2: 278.5 KiB

    // ---- production ----
    proj_kernel<<<dim3(SEQ / 16), dim3(256), 0, stream>>>(
        x, Wq, bq, Wk, bk, Wv, bv, Q, KV);
    flash_v2<1><<<dim3(TOTAL_CHUNKS2), dim3(64), 0, stream>>>(
        Q, KV, partO, partL);
    merge_v2<<<dim3(NQT1), dim3(256), 0, stream>>>(
        partO, partL, (float*)d_out);

    // ---- A/B probes (scratch only) ----
    flash_v1<10><<<dim3(TOTAL_CHUNKS1), dim3(64), 0, stream>>>(
        Q, KV, pO1, pL1);
    flash_v2<10><<<dim3(TOTAL_CHUNKS2), dim3(64), 0, stream>>>(
        Q, KV, pO2, pL2);
}

// Round 11
// 84.910 us; speedup vs baseline: 2.7941x; 2.7941x over previous
//
#include <hip/hip_runtime.h>
#include <hip/hip_fp16.h>

#define SEQ 8192
#define CHUNK 32               // k-tiles (16 keys each) per wave chunk
#define NST 256                // 32-row q-supertiles
#define TOTAL_CHUNKS 2176      // sum over st of ceil((2st+2)/32)
#define NQT 512                // 16-row q-tiles (merge granularity)

typedef __fp16   fp16x2 __attribute__((ext_vector_type(2)));
typedef __fp16   fp16x4 __attribute__((ext_vector_type(4)));
typedef _Float16 half4  __attribute__((ext_vector_type(4)));
typedef _Float16 half8  __attribute__((ext_vector_type(8)));
typedef float   floatx4 __attribute__((ext_vector_type(4)));

// chunks for supertiles 0..n-1; ceil((2j+2)/32) = ceil((j+1)/16)
__device__ __forceinline__ int cum_chunks(int n) {
    const int a = n >> 4, r = n & 15;
    return (a + 1) * (8 * a + r);
}

// pack 4 f32 -> half4 via 2x v_cvt_pkrtz_f16_f32
__device__ __forceinline__ half4 pk4(float a, float b, float c, float d) {
    const fp16x2 lo = __builtin_amdgcn_cvt_pkrtz(a, b);
    const fp16x2 hi = __builtin_amdgcn_cvt_pkrtz(c, d);
    const fp16x4 v  = __builtin_shufflevector(lo, hi, 0, 1, 2, 3);
    return __builtin_bit_cast(half4, v);
}

// ---------------- Kernel 1: QKV projection ----------------
// x[8192][64] f32 -> Q[row][d] fp16 (pre-scaled by 0.25*log2e),
// KV tile-interleaved: per k-tile t a 1KB block; lane L reads 16B at
// KV + t*512h + L*8h: halfs[0..3]=K-frag, halfs[4..7]=V-frag.
__global__ __launch_bounds__(256) void proj_kernel(
    const float* __restrict__ x,
    const float* __restrict__ Wq, const float* __restrict__ bq,
    const float* __restrict__ Wk, const float* __restrict__ bk,
    const float* __restrict__ Wv, const float* __restrict__ bv,
    _Float16* __restrict__ Q, _Float16* __restrict__ KV)
{
    __shared__ float4 xs[16][17];
    __shared__ float4 wqs[16][17];
    __shared__ float4 wks[16][17];
    __shared__ float4 wvs[16][17];

    const int tid  = threadIdx.x;
    const int r    = tid >> 4;
    const int d    = tid & 15;
    const int row0 = blockIdx.x * 16;

    const int rr  = tid >> 4;
    const int cc4 = tid & 15;
    xs[rr][cc4]  = *(const float4*)(x  + (size_t)row0 * 64 + tid * 4);
    wqs[rr][cc4] = *(const float4*)(Wq + tid * 4);
    wks[rr][cc4] = *(const float4*)(Wk + tid * 4);
    wvs[rr][cc4] = *(const float4*)(Wv + tid * 4);
    __syncthreads();

    float aq = 0.f, ak = 0.f, av = 0.f;
#pragma unroll
    for (int kk = 0; kk < 16; ++kk) {
        const float4 xv = xs[r][kk];
        const float4 q4 = wqs[d][kk];
        const float4 k4 = wks[d][kk];
        const float4 v4 = wvs[d][kk];
        aq += xv.x * q4.x; aq += xv.y * q4.y; aq += xv.z * q4.z; aq += xv.w * q4.w;
        ak += xv.x * k4.x; ak += xv.y * k4.y; ak += xv.z * k4.z; ak += xv.w * k4.w;
        av += xv.x * v4.x; av += xv.y * v4.y; av += xv.z * v4.z; av += xv.w * v4.w;
    }
    aq += bq[d];
    ak += bk[d];
    av += bv[d];
    aq *= 0.36067376022224085f;   // (1/sqrt(16)) * log2(e)

    const int row = row0 + r;
    Q[row * 16 + d] = (_Float16)aq;
    _Float16* kvb = KV + (size_t)blockIdx.x * 512;
    kvb[((d >> 2) * 16 + r) * 8 + (d & 3)]     = (_Float16)ak;
    kvb[((r >> 2) * 16 + d) * 8 + 4 + (r & 3)] = (_Float16)av;
}

// ---------------- Kernel 2: 2-q-tile split-K causal flash -----------------
// Chunk = <=32 k-tiles x 32 q-rows (supertile). Each KV tile loaded ONCE
// serves TWO q-frags (round-9 A/B: 6.4 vs 9.2 us for the 1-q-tile version).
// Mask-free tiles end at td0=2*st; td0 is diagonal for lower 16 rows, full
// for upper; td1=td0+1 diagonal for upper, empty for lower.
__global__ __launch_bounds__(64) void flash_kernel(
    const _Float16* __restrict__ Q, const _Float16* __restrict__ KV,
    float* __restrict__ partO, float* __restrict__ partL)
{
    const int bp = (TOTAL_CHUNKS - 1) - (int)blockIdx.x;   // biggest first
    int lo = 0, hi = NST - 1;
#pragma unroll
    for (int it = 0; it < 8; ++it) {          // 2^8 = 256 = NST
        const int mid = (lo + hi + 1) >> 1;
        if (cum_chunks(mid) <= bp) lo = mid; else hi = mid - 1;
    }
    const int st = lo;
    const int c  = bp - cum_chunks(st);
    const int t0 = c * CHUNK;
    const int nk = 2 * st + 2;                // total k-tiles incl. diagonals
    int t1 = t0 + CHUNK;
    if (t1 > nk) t1 = nk;
    const int td0 = 2 * st;
    const int nd  = (t1 < td0) ? t1 : td0;    // end of mask-free tiles

    const int L    = threadIdx.x;
    const int m16  = L & 15;
    const int quad = L >> 4;
    const int qrA  = st * 32 + m16;           // lower-half q-row
    const int qrB  = qrA + 16;                // upper-half q-row

    const half4 qfA = *(const half4*)(Q + (size_t)qrA * 16 + quad * 4);
    const half4 qfB = *(const half4*)(Q + (size_t)qrB * 16 + quad * 4);
    const _Float16* kvbase = KV + (size_t)L * 8;   // + t*512 halfs per tile

    const floatx4 z4 = {0.f, 0.f, 0.f, 0.f};

    auto ldkv = [&](int t) -> half8 {
        return *(const half8*)(kvbase + (size_t)t * 512);
    };

    float   lA = 0.f, lB = 0.f;
    floatx4 accA = {0.f, 0.f, 0.f, 0.f};
    floatx4 accB = {0.f, 0.f, 0.f, 0.f};

    auto body2 = [&](half8 kv) {
        const half4 kf = __builtin_shufflevector(kv, kv, 0, 1, 2, 3);
        const half4 vf = __builtin_shufflevector(kv, kv, 4, 5, 6, 7);
        floatx4 sA = __builtin_amdgcn_mfma_f32_16x16x16f16(kf, qfA, z4, 0, 0, 0);
        floatx4 sB = __builtin_amdgcn_mfma_f32_16x16x16f16(kf, qfB, z4, 0, 0, 0);
        const float a0 = __builtin_amdgcn_exp2f(sA[0]);
        const float a1 = __builtin_amdgcn_exp2f(sA[1]);
        const float a2 = __builtin_amdgcn_exp2f(sA[2]);
        const float a3 = __builtin_amdgcn_exp2f(sA[3]);
        const float b0 = __builtin_amdgcn_exp2f(sB[0]);
        const float b1 = __builtin_amdgcn_exp2f(sB[1]);
        const float b2 = __builtin_amdgcn_exp2f(sB[2]);
        const float b3 = __builtin_amdgcn_exp2f(sB[3]);
        lA += (a0 + a1) + (a2 + a3);
        lB += (b0 + b1) + (b2 + b3);
        const half4 pA = pk4(a0, a1, a2, a3);
        const half4 pB = pk4(b0, b1, b2, b3);
        accA = __builtin_amdgcn_mfma_f32_16x16x16f16(vf, pA, accA, 0, 0, 0);
        accB = __builtin_amdgcn_mfma_f32_16x16x16f16(vf, pB, accB, 0, 0, 0);
    };

    // mask-free tiles (nd - t0 is always even)
    int kt = t0;
    if (kt + 1 < nd) {
        half8 v0 = ldkv(kt);
        half8 v1 = ldkv(kt + 1);
        for (; kt + 3 < nd; kt += 2) {
            const half8 n0 = ldkv(kt + 2);
            const half8 n1 = ldkv(kt + 3);
            __builtin_amdgcn_s_setprio(1);
            body2(v0);
            body2(v1);
            __builtin_amdgcn_s_setprio(0);
            v0 = n0; v1 = n1;
        }
        body2(v0);
        body2(v1);
        kt += 2;
    }

    if (t1 == nk) {                       // last chunk: diagonal tiles
        {   // td0: diagonal for A, full for B
            const half8 kv = ldkv(td0);
            const half4 kf = __builtin_shufflevector(kv, kv, 0, 1, 2, 3);
            const half4 vf = __builtin_shufflevector(kv, kv, 4, 5, 6, 7);
            floatx4 sA = __builtin_amdgcn_mfma_f32_16x16x16f16(kf, qfA, z4, 0, 0, 0);
#pragma unroll
            for (int r = 0; r < 4; ++r)
                if (quad * 4 + r > m16) sA[r] = -1.0e30f;  // exp2 -> 0
            floatx4 sB = __builtin_amdgcn_mfma_f32_16x16x16f16(kf, qfB, z4, 0, 0, 0);
            const float a0 = __builtin_amdgcn_exp2f(sA[0]);
            const float a1 = __builtin_amdgcn_exp2f(sA[1]);
            const float a2 = __builtin_amdgcn_exp2f(sA[2]);
            const float a3 = __builtin_amdgcn_exp2f(sA[3]);
            const float b0 = __builtin_amdgcn_exp2f(sB[0]);
            const float b1 = __builtin_amdgcn_exp2f(sB[1]);
            const float b2 = __builtin_amdgcn_exp2f(sB[2]);
            const float b3 = __builtin_amdgcn_exp2f(sB[3]);
            lA += (a0 + a1) + (a2 + a3);
            lB += (b0 + b1) + (b2 + b3);
            const half4 pA = pk4(a0, a1, a2, a3);
            const half4 pB = pk4(b0, b1, b2, b3);
            accA = __builtin_amdgcn_mfma_f32_16x16x16f16(vf, pA, accA, 0, 0, 0);
            accB = __builtin_amdgcn_mfma_f32_16x16x16f16(vf, pB, accB, 0, 0, 0);
        }
        {   // td1: diagonal for B, empty for A
            const half8 kv = ldkv(td0 + 1);
            const half4 kf = __builtin_shufflevector(kv, kv, 0, 1, 2, 3);
            const half4 vf = __builtin_shufflevector(kv, kv, 4, 5, 6, 7);
            floatx4 sB = __builtin_amdgcn_mfma_f32_16x16x16f16(kf, qfB, z4, 0, 0, 0);
#pragma unroll
            for (int r = 0; r < 4; ++r)
                if (quad * 4 + r > m16) sB[r] = -1.0e30f;
            const float b0 = __builtin_amdgcn_exp2f(sB[0]);
            const float b1 = __builtin_amdgcn_exp2f(sB[1]);
            const float b2 = __builtin_amdgcn_exp2f(sB[2]);
            const float b3 = __builtin_amdgcn_exp2f(sB[3]);
            lB += (b0 + b1) + (b2 + b3);
            const half4 pB = pk4(b0, b1, b2, b3);
            accB = __builtin_amdgcn_mfma_f32_16x16x16f16(vf, pB, accB, 0, 0, 0);
        }
    }

    lA += __shfl_xor(lA, 16);
    lA += __shfl_xor(lA, 32);
    lB += __shfl_xor(lB, 16);
    lB += __shfl_xor(lB, 32);

    float* po = partO + (size_t)bp * 512;
    *(floatx4*)(po + m16 * 16 + quad * 4)       = accA;
    *(floatx4*)(po + 256 + m16 * 16 + quad * 4) = accB;
    if (quad == 0) {
        partL[(size_t)bp * 32 + m16]      = lA;
        partL[(size_t)bp * 32 + 16 + m16] = lB;
    }
}

// ---------------- Kernel 3: linear merge over supertile chunks ------------
__global__ __launch_bounds__(256) void merge_kernel(
    const float* __restrict__ partO, const float* __restrict__ partL,
    float* __restrict__ out)
{
    const int qt = blockIdx.x;            // 512 q-tiles (16 rows)
    const int t  = threadIdx.x;           // q = t>>4, d = t&15
    const int st = qt >> 1;
    const int hf = qt & 1;                // 0 = lower half, 1 = upper half

    const int base = cum_chunks(st);
    const int nc   = (st >> 4) + 1;       // ceil((2st+2)/32)

    const float* po = partO + (size_t)base * 512 + hf * 256 + t;
    const float* pl = partL + (size_t)base * 32 + hf * 16 + (t >> 4);
    float Ls = 0.f, O = 0.f;
    for (int c = 0; c < nc; ++c, po += 512, pl += 32) {
        O  += *po;
        Ls += *pl;
    }
    out[(size_t)qt * 256 + t] = O / Ls;
}

extern "C" void kernel_launch(void* const* d_in, const int* in_sizes, int n_in,
                              void* d_out, int out_size, void* d_ws, size_t ws_size,
                              hipStream_t stream) {
    const float* x  = (const float*)d_in[0];
    const float* Wq = (const float*)d_in[1];
    const float* bq = (const float*)d_in[2];
    const float* Wk = (const float*)d_in[3];
    const float* bk = (const float*)d_in[4];
    const float* Wv = (const float*)d_in[5];
    const float* bv = (const float*)d_in[6];

    char* ws = (char*)d_ws;
    _Float16* Q     = (_Float16*)(ws);            // 256 KiB
    _Float16* KV    = (_Float16*)(ws + 262144);   // 512 KiB (512 tiles x 1KB)
    float*    partO = (float*)(ws + 786432);      // 2176*512*4 = 4.456 MiB
    float*    partL = (float*)(ws + 786432 + 4456448);  // 2176*32*4 = 278.5 KiB

    proj_kernel<<<dim3(SEQ / 16), dim3(256), 0, stream>>>(
        x, Wq, bq, Wk, bk, Wv, bv, Q, KV);
    flash_kernel<<<dim3(TOTAL_CHUNKS), dim3(64), 0, stream>>>(
        Q, KV, partO, partL);
    merge_kernel<<<dim3(NQT), dim3(256), 0, stream>>>(
        partO, partL, (float*)d_out);
}

// Round 12
// 84.266 us; speedup vs baseline: 2.8154x; 1.0076x over previous
//
#include <hip/hip_runtime.h>
#include <hip/hip_fp16.h>

#define SEQ 8192
#define CHUNK 32               // k-tiles (16 keys each) per chunk
#define NST 256                // 32-row q-supertiles
#define TOTAL_CHUNKS 2176      // sum over st of ceil((2st+2)/32)
#define NQT 512                // 16-row q-tiles (merge granularity)

typedef _Float16 half4  __attribute__((ext_vector_type(4)));
typedef _Float16 half8  __attribute__((ext_vector_type(8)));
typedef float   floatx4 __attribute__((ext_vector_type(4)));

// chunks for supertiles 0..n-1; ceil((2j+2)/32) = ceil((j+1)/16)
__device__ __forceinline__ int cum_chunks(int n) {
    const int a = n >> 4, r = n & 15;
    return (a + 1) * (8 * a + r);
}

// ---------------- Kernel 1: QKV projection ----------------
// x[8192][64] f32 -> Q[row][d] fp16 (pre-scaled by 0.25*log2e),
// KV tile-interleaved: per k-tile t a 1KB block; lane L reads 16B at
// KV + t*512h + L*8h: halfs[0..3]=K-frag, halfs[4..7]=V-frag.
__global__ __launch_bounds__(256) void proj_kernel(
    const float* __restrict__ x,
    const float* __restrict__ Wq, const float* __restrict__ bq,
    const float* __restrict__ Wk, const float* __restrict__ bk,
    const float* __restrict__ Wv, const float* __restrict__ bv,
    _Float16* __restrict__ Q, _Float16* __restrict__ KV)
{
    __shared__ float4 xs[16][17];
    __shared__ float4 wqs[16][17];
    __shared__ float4 wks[16][17];
    __shared__ float4 wvs[16][17];

    const int tid  = threadIdx.x;
    const int r    = tid >> 4;
    const int d    = tid & 15;
    const int row0 = blockIdx.x * 16;

    const int rr  = tid >> 4;
    const int cc4 = tid & 15;
    xs[rr][cc4]  = *(const float4*)(x  + (size_t)row0 * 64 + tid * 4);
    wqs[rr][cc4] = *(const float4*)(Wq + tid * 4);
    wks[rr][cc4] = *(const float4*)(Wk + tid * 4);
    wvs[rr][cc4] = *(const float4*)(Wv + tid * 4);
    __syncthreads();

    float aq = 0.f, ak = 0.f, av = 0.f;
#pragma unroll
    for (int kk = 0; kk < 16; ++kk) {
        const float4 xv = xs[r][kk];
        const float4 q4 = wqs[d][kk];
        const float4 k4 = wks[d][kk];
        const float4 v4 = wvs[d][kk];
        aq += xv.x * q4.x; aq += xv.y * q4.y; aq += xv.z * q4.z; aq += xv.w * q4.w;
        ak += xv.x * k4.x; ak += xv.y * k4.y; ak += xv.z * k4.z; ak += xv.w * k4.w;
        av += xv.x * v4.x; av += xv.y * v4.y; av += xv.z * v4.z; av += xv.w * v4.w;
    }
    aq += bq[d];
    ak += bk[d];
    av += bv[d];
    aq *= 0.36067376022224085f;   // (1/sqrt(16)) * log2(e)

    const int row = row0 + r;
    Q[row * 16 + d] = (_Float16)aq;
    _Float16* kvb = KV + (size_t)blockIdx.x * 512;
    kvb[((d >> 2) * 16 + r) * 8 + (d & 3)]     = (_Float16)ak;
    kvb[((r >> 2) * 16 + d) * 8 + 4 + (r & 3)] = (_Float16)av;
}

// ---------------- Kernel 2: 2-q-tile, 2-wave split-K causal flash ---------
// Chunk = <=32 k-tiles x 32 q-rows (supertile). Each KV tile loaded ONCE
// serves TWO q-frags (v2 win, probe-verified r9). TWO waves per block split
// the chunk's tiles by parity -> 4352 waves total (v1-level TLP to hide
// cold cross-XCD KV latency; r11 showed 2176 waves lose ~4us to cold reads
// that the warm REP-probe couldn't see). LDS combine keeps partial traffic
// identical to 1-wave blocks. t0 and td0 are both even -> wave 0 owns the
// td0 diagonal (diag for A rows, full for B rows), wave 1 owns td1 (diag
// for B, empty for A).
__global__ __launch_bounds__(128) void flash_kernel(
    const _Float16* __restrict__ Q, const _Float16* __restrict__ KV,
    float* __restrict__ partO, float* __restrict__ partL)
{
    const int bp = (TOTAL_CHUNKS - 1) - (int)blockIdx.x;   // biggest first
    int lo = 0, hi = NST - 1;
#pragma unroll
    for (int it = 0; it < 8; ++it) {          // 2^8 = 256 = NST
        const int mid = (lo + hi + 1) >> 1;
        if (cum_chunks(mid) <= bp) lo = mid; else hi = mid - 1;
    }
    const int st = lo;
    const int c  = bp - cum_chunks(st);
    const int t0 = c * CHUNK;
    const int nk = 2 * st + 2;                // total k-tiles incl. diagonals
    int t1 = t0 + CHUNK;
    if (t1 > nk) t1 = nk;
    const int td0 = 2 * st;
    const int nd  = (t1 < td0) ? t1 : td0;    // end of mask-free tiles

    const int tid  = threadIdx.x;
    const int w    = tid >> 6;                // wave id 0/1
    const int L    = tid & 63;
    const int m16  = L & 15;
    const int quad = L >> 4;
    const int qrA  = st * 32 + m16;           // lower-half q-row
    const int qrB  = qrA + 16;                // upper-half q-row

    const half4 qfA = *(const half4*)(Q + (size_t)qrA * 16 + quad * 4);
    const half4 qfB = *(const half4*)(Q + (size_t)qrB * 16 + quad * 4);
    const _Float16* kvbase = KV + (size_t)L * 8;   // + t*512 halfs per tile

    const floatx4 z4 = {0.f, 0.f, 0.f, 0.f};

    auto ldkv = [&](int t) -> half8 {
        return *(const half8*)(kvbase + (size_t)t * 512);
    };

    float   lA = 0.f, lB = 0.f;
    floatx4 accA = {0.f, 0.f, 0.f, 0.f};
    floatx4 accB = {0.f, 0.f, 0.f, 0.f};

    auto body2 = [&](half8 kv) {
        const half4 kf = __builtin_shufflevector(kv, kv, 0, 1, 2, 3);
        const half4 vf = __builtin_shufflevector(kv, kv, 4, 5, 6, 7);
        floatx4 sA = __builtin_amdgcn_mfma_f32_16x16x16f16(kf, qfA, z4, 0, 0, 0);
        floatx4 sB = __builtin_amdgcn_mfma_f32_16x16x16f16(kf, qfB, z4, 0, 0, 0);
        const float a0 = __builtin_amdgcn_exp2f(sA[0]);
        const float a1 = __builtin_amdgcn_exp2f(sA[1]);
        const float a2 = __builtin_amdgcn_exp2f(sA[2]);
        const float a3 = __builtin_amdgcn_exp2f(sA[3]);
        const float b0 = __builtin_amdgcn_exp2f(sB[0]);
        const float b1 = __builtin_amdgcn_exp2f(sB[1]);
        const float b2 = __builtin_amdgcn_exp2f(sB[2]);
        const float b3 = __builtin_amdgcn_exp2f(sB[3]);
        lA += (a0 + a1) + (a2 + a3);
        lB += (b0 + b1) + (b2 + b3);
        const half4 pA = {(_Float16)a0, (_Float16)a1, (_Float16)a2, (_Float16)a3};
        const half4 pB = {(_Float16)b0, (_Float16)b1, (_Float16)b2, (_Float16)b3};
        accA = __builtin_amdgcn_mfma_f32_16x16x16f16(vf, pA, accA, 0, 0, 0);
        accB = __builtin_amdgcn_mfma_f32_16x16x16f16(vf, pB, accB, 0, 0, 0);
    };

    // this wave's mask-free tiles: kt = t0+w, t0+w+2, ... (< nd);
    // nd - t0 is always even, so the waves get equal +/-0 tile counts.
    int kt = t0 + w;
    if (kt + 2 < nd) {                        // >= 2 tiles for this wave
        half8 v0 = ldkv(kt);
        half8 v1 = ldkv(kt + 2);
        for (; kt + 6 < nd; kt += 4) {        // 2-deep ring over stride-2 tiles
            const half8 n0 = ldkv(kt + 4);
            const half8 n1 = ldkv(kt + 6);
            __builtin_amdgcn_s_setprio(1);
            body2(v0);
            body2(v1);
            __builtin_amdgcn_s_setprio(0);
            v0 = n0; v1 = n1;
        }
        body2(v0);
        body2(v1);
        kt += 4;
    }
    if (kt < nd)
        body2(ldkv(kt));

    if (t1 == nk) {                       // last chunk: diagonal tiles
        if (w == 0) {                     // td0: diagonal for A, full for B
            const half8 kv = ldkv(td0);
            const half4 kf = __builtin_shufflevector(kv, kv, 0, 1, 2, 3);
            const half4 vf = __builtin_shufflevector(kv, kv, 4, 5, 6, 7);
            floatx4 sA = __builtin_amdgcn_mfma_f32_16x16x16f16(kf, qfA, z4, 0, 0, 0);
#pragma unroll
            for (int r = 0; r < 4; ++r)
                if (quad * 4 + r > m16) sA[r] = -1.0e30f;  // exp2 -> 0
            floatx4 sB = __builtin_amdgcn_mfma_f32_16x16x16f16(kf, qfB, z4, 0, 0, 0);
            const float a0 = __builtin_amdgcn_exp2f(sA[0]);
            const float a1 = __builtin_amdgcn_exp2f(sA[1]);
            const float a2 = __builtin_amdgcn_exp2f(sA[2]);
            const float a3 = __builtin_amdgcn_exp2f(sA[3]);
            const float b0 = __builtin_amdgcn_exp2f(sB[0]);
            const float b1 = __builtin_amdgcn_exp2f(sB[1]);
            const float b2 = __builtin_amdgcn_exp2f(sB[2]);
            const float b3 = __builtin_amdgcn_exp2f(sB[3]);
            lA += (a0 + a1) + (a2 + a3);
            lB += (b0 + b1) + (b2 + b3);
            const half4 pA = {(_Float16)a0, (_Float16)a1, (_Float16)a2, (_Float16)a3};
            const half4 pB = {(_Float16)b0, (_Float16)b1, (_Float16)b2, (_Float16)b3};
            accA = __builtin_amdgcn_mfma_f32_16x16x16f16(vf, pA, accA, 0, 0, 0);
            accB = __builtin_amdgcn_mfma_f32_16x16x16f16(vf, pB, accB, 0, 0, 0);
        } else {                          // td1: diagonal for B, empty for A
            const half8 kv = ldkv(td0 + 1);
            const half4 kf = __builtin_shufflevector(kv, kv, 0, 1, 2, 3);
            const half4 vf = __builtin_shufflevector(kv, kv, 4, 5, 6, 7);
            floatx4 sB = __builtin_amdgcn_mfma_f32_16x16x16f16(kf, qfB, z4, 0, 0, 0);
#pragma unroll
            for (int r = 0; r < 4; ++r)
                if (quad * 4 + r > m16) sB[r] = -1.0e30f;
            const float b0 = __builtin_amdgcn_exp2f(sB[0]);
            const float b1 = __builtin_amdgcn_exp2f(sB[1]);
            const float b2 = __builtin_amdgcn_exp2f(sB[2]);
            const float b3 = __builtin_amdgcn_exp2f(sB[3]);
            lB += (b0 + b1) + (b2 + b3);
            const half4 pB = {(_Float16)b0, (_Float16)b1, (_Float16)b2, (_Float16)b3};
            accB = __builtin_amdgcn_mfma_f32_16x16x16f16(vf, pB, accB, 0, 0, 0);
        }
    }

    lA += __shfl_xor(lA, 16);
    lA += __shfl_xor(lA, 32);
    lB += __shfl_xor(lB, 16);
    lB += __shfl_xor(lB, 32);

    // cross-wave combine in LDS (partial traffic unchanged vs 1-wave blocks)
    __shared__ floatx4 sOA[64];
    __shared__ floatx4 sOB[64];
    __shared__ float   sLA[16];
    __shared__ float   sLB[16];
    if (w == 1) {
        sOA[L] = accA;
        sOB[L] = accB;
        if (quad == 0) { sLA[m16] = lA; sLB[m16] = lB; }
    }
    __syncthreads();
    if (w == 0) {
        const floatx4 oa = sOA[L];
        const floatx4 ob = sOB[L];
        accA[0] += oa[0]; accA[1] += oa[1]; accA[2] += oa[2]; accA[3] += oa[3];
        accB[0] += ob[0]; accB[1] += ob[1]; accB[2] += ob[2]; accB[3] += ob[3];
        lA += sLA[m16];
        lB += sLB[m16];

        float* po = partO + (size_t)bp * 512;
        *(floatx4*)(po + m16 * 16 + quad * 4)       = accA;
        *(floatx4*)(po + 256 + m16 * 16 + quad * 4) = accB;
        if (quad == 0) {
            partL[(size_t)bp * 32 + m16]      = lA;
            partL[(size_t)bp * 32 + 16 + m16] = lB;
        }
    }
}

// ---------------- Kernel 3: linear merge over supertile chunks ------------
__global__ __launch_bounds__(256) void merge_kernel(
    const float* __restrict__ partO, const float* __restrict__ partL,
    float* __restrict__ out)
{
    const int qt = blockIdx.x;            // 512 q-tiles (16 rows)
    const int t  = threadIdx.x;           // q = t>>4, d = t&15
    const int st = qt >> 1;
    const int hf = qt & 1;                // 0 = lower half, 1 = upper half

    const int base = cum_chunks(st);
    const int nc   = (st >> 4) + 1;       // ceil((2st+2)/32)

    const float* po = partO + (size_t)base * 512 + hf * 256 + t;
    const float* pl = partL + (size_t)base * 32 + hf * 16 + (t >> 4);
    float Ls = 0.f, O = 0.f;
    for (int c = 0; c < nc; ++c, po += 512, pl += 32) {
        O  += *po;
        Ls += *pl;
    }
    out[(size_t)qt * 256 + t] = O / Ls;
}

extern "C" void kernel_launch(void* const* d_in, const int* in_sizes, int n_in,
                              void* d_out, int out_size, void* d_ws, size_t ws_size,
                              hipStream_t stream) {
    const float* x  = (const float*)d_in[0];
    const float* Wq = (const float*)d_in[1];
    const float* bq = (const float*)d_in[2];
    const float* Wk = (const float*)d_in[3];
    const float* bk = (const float*)d_in[4];
    const float* Wv = (const float*)d_in[5];
    const float* bv = (const float*)d_in[6];

    char* ws = (char*)d_ws;
    _Float16* Q     = (_Float16*)(ws);            // 256 KiB
    _Float16* KV    = (_Float16*)(ws + 262144);   // 512 KiB (512 tiles x 1KB)
    float*    partO = (float*)(ws + 786432);      // 2176*512*4 = 4.456 MiB
    float*    partL = (float*)(ws + 786432 + 4456448);  // 2176*32*4 = 278.5 KiB

    proj_kernel<<<dim3(SEQ / 16), dim3(256), 0, stream>>>(
        x, Wq, bq, Wk, bk, Wv, bv, Q, KV);
    flash_kernel<<<dim3(TOTAL_CHUNKS), dim3(128), 0, stream>>>(
        Q, KV, partO, partL);
    merge_kernel<<<dim3(NQT), dim3(256), 0, stream>>>(
        partO, partL, (float*)d_out);
}

// Round 13
// 83.234 us; speedup vs baseline: 2.8503x; 1.0124x over previous
//
#include <hip/hip_runtime.h>
#include <hip/hip_fp16.h>

#define SEQ 8192
#define NQT 512                // 16-row q-tiles
#define CHUNK 32               // k-tiles (of 16 keys) per wave chunk
#define TOTAL_CHUNKS 4352      // S(512) = sum over qt of ceil((qt+1)/32)

typedef _Float16 half4  __attribute__((ext_vector_type(4)));
typedef _Float16 half8  __attribute__((ext_vector_type(8)));
typedef float   floatx4 __attribute__((ext_vector_type(4)));

// S(n) = chunks for q-tiles 0..n-1 = n + 16a(a-1) + a*r, n = 32a + r
__device__ __forceinline__ int cum_chunks(int n) {
    const int a = n >> 5, r = n & 31;
    return n + 16 * a * (a - 1) + a * r;
}

// ---------------- Kernel 1: QKV projection ----------------
__global__ __launch_bounds__(256) void proj_kernel(
    const float* __restrict__ x,
    const float* __restrict__ Wq, const float* __restrict__ bq,
    const float* __restrict__ Wk, const float* __restrict__ bk,
    const float* __restrict__ Wv, const float* __restrict__ bv,
    _Float16* __restrict__ Q, _Float16* __restrict__ KV)
{
    __shared__ float4 xs[16][17];
    __shared__ float4 wqs[16][17];
    __shared__ float4 wks[16][17];
    __shared__ float4 wvs[16][17];

    const int tid  = threadIdx.x;
    const int r    = tid >> 4;
    const int d    = tid & 15;
    const int row0 = blockIdx.x * 16;

    const int rr  = tid >> 4;
    const int cc4 = tid & 15;
    xs[rr][cc4]  = *(const float4*)(x  + (size_t)row0 * 64 + tid * 4);
    wqs[rr][cc4] = *(const float4*)(Wq + tid * 4);
    wks[rr][cc4] = *(const float4*)(Wk + tid * 4);
    wvs[rr][cc4] = *(const float4*)(Wv + tid * 4);
    __syncthreads();

    float aq = 0.f, ak = 0.f, av = 0.f;
#pragma unroll
    for (int kk = 0; kk < 16; ++kk) {
        const float4 xv = xs[r][kk];
        const float4 q4 = wqs[d][kk];
        const float4 k4 = wks[d][kk];
        const float4 v4 = wvs[d][kk];
        aq += xv.x * q4.x; aq += xv.y * q4.y; aq += xv.z * q4.z; aq += xv.w * q4.w;
        ak += xv.x * k4.x; ak += xv.y * k4.y; ak += xv.z * k4.z; ak += xv.w * k4.w;
        av += xv.x * v4.x; av += xv.y * v4.y; av += xv.z * v4.z; av += xv.w * v4.w;
    }
    aq += bq[d];
    ak += bk[d];
    av += bv[d];
    aq *= 0.36067376022224085f;   // (1/sqrt(16)) * log2(e)

    const int row = row0 + r;
    Q[row * 16 + d] = (_Float16)aq;
    _Float16* kvb = KV + (size_t)blockIdx.x * 512;
    kvb[((d >> 2) * 16 + r) * 8 + (d & 3)]     = (_Float16)ak;
    kvb[((r >> 2) * 16 + d) * 8 + 4 + (r & 3)] = (_Float16)av;
}

// ---------------- Kernel 2: balanced split-K causal flash attention -------
// One wave per chunk of <=32 k-tiles. K+V fragments interleaved: ONE
// global_load_dwordx4 per tile body. 4-deep software pipeline.
// Best verified configuration (round 6: 83.39 us).
__global__ __launch_bounds__(64) void flash_kernel(
    const _Float16* __restrict__ Q, const _Float16* __restrict__ KV,
    float* __restrict__ partO, float* __restrict__ partL)
{
    const int bp = (TOTAL_CHUNKS - 1) - (int)blockIdx.x;
    int lo = 0, hi = NQT - 1;
#pragma unroll
    for (int it = 0; it < 9; ++it) {          // 2^9 = 512 >= NQT
        const int mid = (lo + hi + 1) >> 1;
        if (cum_chunks(mid) <= bp) lo = mid; else hi = mid - 1;
    }
    const int qt = lo;
    const int c  = bp - cum_chunks(qt);
    const int t0 = c * CHUNK;
    int t1 = t0 + CHUNK;
    if (t1 > qt + 1) t1 = qt + 1;
    const int nd = (t1 > qt) ? qt : t1;       // end of mask-free tiles

    const int L    = threadIdx.x;
    const int m16  = L & 15;
    const int quad = L >> 4;
    const int qrow = qt * 16 + m16;

    const half4 qf = *(const half4*)(Q + (size_t)qrow * 16 + quad * 4);
    const _Float16* kvbase = KV + (size_t)L * 8;   // + kt*512 halfs per tile

    float   l0 = 0.f, l1 = 0.f;
    floatx4 acc0 = {0.f, 0.f, 0.f, 0.f};
    floatx4 acc1 = {0.f, 0.f, 0.f, 0.f};
    const floatx4 z4 = {0.f, 0.f, 0.f, 0.f};

    auto ldkv = [&](int t) -> half8 {
        return *(const half8*)(kvbase + (size_t)t * 512);
    };

    auto body = [&](half8 kv, floatx4& acc, float& ls) {
        const half4 kf = __builtin_shufflevector(kv, kv, 0, 1, 2, 3);
        const half4 vf = __builtin_shufflevector(kv, kv, 4, 5, 6, 7);
        floatx4 s = __builtin_amdgcn_mfma_f32_16x16x16f16(kf, qf, z4, 0, 0, 0);
        const float p0 = __builtin_amdgcn_exp2f(s[0]);
        const float p1 = __builtin_amdgcn_exp2f(s[1]);
        const float p2 = __builtin_amdgcn_exp2f(s[2]);
        const float p3 = __builtin_amdgcn_exp2f(s[3]);
        ls += (p0 + p1) + (p2 + p3);
        const half4 pf = {(_Float16)p0, (_Float16)p1, (_Float16)p2, (_Float16)p3};
        acc = __builtin_amdgcn_mfma_f32_16x16x16f16(vf, pf, acc, 0, 0, 0);
    };

    int kt = t0;
    if (nd - kt >= 4) {
        half8 b0 = ldkv(kt);
        half8 b1 = ldkv(kt + 1);
        half8 b2 = ldkv(kt + 2);
        half8 b3 = ldkv(kt + 3);
        for (; kt + 7 < nd; kt += 4) {        // 4-deep pipelined hot loop
            const half8 n0 = ldkv(kt + 4);
            const half8 n1 = ldkv(kt + 5);
            const half8 n2 = ldkv(kt + 6);
            const half8 n3 = ldkv(kt + 7);
            __builtin_amdgcn_s_setprio(1);
            body(b0, acc0, l0);
            body(b1, acc1, l1);
            body(b2, acc0, l0);
            body(b3, acc1, l1);
            __builtin_amdgcn_s_setprio(0);
            b0 = n0; b1 = n1; b2 = n2; b3 = n3;
        }
        body(b0, acc0, l0);
        body(b1, acc1, l1);
        body(b2, acc0, l0);
        body(b3, acc1, l1);
        kt += 4;
    }
    for (; kt + 1 < nd; kt += 2) {            // short-chunk / tail pairs
        body(ldkv(kt),     acc0, l0);
        body(ldkv(kt + 1), acc1, l1);
    }
    if (kt < nd)
        body(ldkv(kt), acc0, l0);

    if (t1 == qt + 1) {                      // peeled diagonal tile
        const int k0 = qt * 16;
        const half8 kv = ldkv(qt);
        const half4 kf = __builtin_shufflevector(kv, kv, 0, 1, 2, 3);
        const half4 vf = __builtin_shufflevector(kv, kv, 4, 5, 6, 7);
        floatx4 s = __builtin_amdgcn_mfma_f32_16x16x16f16(kf, qf, z4, 0, 0, 0);
#pragma unroll
        for (int r = 0; r < 4; ++r)
            if (k0 + quad * 4 + r > qrow) s[r] = -1.0e30f;  // exp2 -> 0
        const float p0 = __builtin_amdgcn_exp2f(s[0]);
        const float p1 = __builtin_amdgcn_exp2f(s[1]);
        const float p2 = __builtin_amdgcn_exp2f(s[2]);
        const float p3 = __builtin_amdgcn_exp2f(s[3]);
        l1 += (p0 + p1) + (p2 + p3);
        const half4 pf = {(_Float16)p0, (_Float16)p1, (_Float16)p2, (_Float16)p3};
        acc1 = __builtin_amdgcn_mfma_f32_16x16x16f16(vf, pf, acc1, 0, 0, 0);
    }

    floatx4 acc = {acc0[0] + acc1[0], acc0[1] + acc1[1],
                   acc0[2] + acc1[2], acc0[3] + acc1[3]};
    float lsum = l0 + l1;
    lsum += __shfl_xor(lsum, 16);
    lsum += __shfl_xor(lsum, 32);

    *(floatx4*)(partO + (size_t)bp * 256 + m16 * 16 + quad * 4) = acc;
    if (quad == 0) partL[(size_t)bp * 16 + m16] = lsum;
}

// ---------------- Kernel 3: linear merge (coalesced) ----------------------
__global__ __launch_bounds__(256) void merge_kernel(
    const float* __restrict__ partO, const float* __restrict__ partL,
    float* __restrict__ out)
{
    const int qt = blockIdx.x;           // 512 q-tiles
    const int t  = threadIdx.x;          // q = t>>4, d = t&15

    const int base = cum_chunks(qt);
    const int nc   = (qt >> 5) + 1;      // ceil((qt+1)/32)

    const float* po = partO + (size_t)base * 256 + t;
    const float* pl = partL + (size_t)base * 16 + (t >> 4);
    float Ls = 0.f, O = 0.f;
    for (int c = 0; c < nc; ++c, po += 256, pl += 16) {
        O  += *po;
        Ls += *pl;
    }
    out[(size_t)qt * 256 + t] = O / Ls;
}

extern "C" void kernel_launch(void* const* d_in, const int* in_sizes, int n_in,
                              void* d_out, int out_size, void* d_ws, size_t ws_size,
                              hipStream_t stream) {
    const float* x  = (const float*)d_in[0];
    const float* Wq = (const float*)d_in[1];
    const float* bq = (const float*)d_in[2];
    const float* Wk = (const float*)d_in[3];
    const float* bk = (const float*)d_in[4];
    const float* Wv = (const float*)d_in[5];
    const float* bv = (const float*)d_in[6];

    char* ws = (char*)d_ws;
    _Float16* Q     = (_Float16*)(ws);            // 256 KiB
    _Float16* KV    = (_Float16*)(ws + 262144);   // 512 KiB (512 tiles x 1KB)
    float*    partO = (float*)(ws + 786432);      // 4352*256*4 = 4.25 MiB
    float*    partL = (float*)(ws + 786432 + 4456448);  // 4352*16*4 = 272 KiB

    proj_kernel<<<dim3(SEQ / 16), dim3(256), 0, stream>>>(
        x, Wq, bq, Wk, bk, Wv, bv, Q, KV);
    flash_kernel<<<dim3(TOTAL_CHUNKS), dim3(64), 0, stream>>>(
        Q, KV, partO, partL);
    merge_kernel<<<dim3(NQT), dim3(256), 0, stream>>>(
        partO, partL, (float*)d_out);
}